// Round 6
// baseline (281.194 us; speedup 1.0000x reference)
//
#include <hip/hip_runtime.h>
#include <hip/hip_bf16.h>

#define B_SZ  4096
#define IN_F  512
#define OUT_F 512
#define NC    64
#define PAIRS 32768               // OUT_F * NC
#define TOT   (IN_F * PAIRS)      // 16.8M
#define KTOT  (IN_F + NC)         // 576: combined GEMM K
#define RCH   32                  // k1 row-chunks (16 rows each)

typedef __attribute__((ext_vector_type(8))) short bf16x8;
typedef __attribute__((ext_vector_type(4))) float f32x4;

static __device__ inline unsigned short f2bf(float f) {
    __hip_bfloat16 h = __float2bfloat16(f);   // RNE
    return *(unsigned short*)&h;
}

// ---------------------------------------------------------------------------
// K1: partial c_sum + kl — EXACT R1/R7 standalone configuration (46.6 us,
// 2.25 TB/s HBM). R3/R4 proved ANY prep fused into this grid loses
// (interleave: 67.8us; appended: 75.3us). Standalone, untouched.
// ---------------------------------------------------------------------------
__global__ __launch_bounds__(512)
void k1_partial(const float* __restrict__ cm,
                const float* __restrict__ clv,
                const float* __restrict__ eps,
                float* __restrict__ part,
                float* __restrict__ klpart,
                int S) {
    int pb = blockIdx.x & 15;            // pair-slice: 2048 pairs (8 KB/row)
    int rc = blockIdx.x >> 4;            // row-chunk: rows rc*16..+16
    int p4 = pb * 2048 + (threadIdx.x << 2);
    float Sf = (float)S;

    f32x4 s = {0.f, 0.f, 0.f, 0.f};
    float klp = 0.f;

    for (int g = 0; g < 2; ++g) {
        size_t base = (size_t)(rc * 16 + g * 8) * PAIRS + p4;
        f32x4 M[8], LV[8], ES[8];
#pragma unroll
        for (int ii = 0; ii < 8; ++ii)
            M[ii] = __builtin_nontemporal_load((const f32x4*)(cm + base + (size_t)ii * PAIRS));
#pragma unroll
        for (int ii = 0; ii < 8; ++ii)
            LV[ii] = __builtin_nontemporal_load((const f32x4*)(clv + base + (size_t)ii * PAIRS));
#pragma unroll
        for (int ii = 0; ii < 8; ++ii)
            ES[ii] = __builtin_nontemporal_load((const f32x4*)(eps + base + (size_t)ii * PAIRS));
        for (int si = 1; si < S; ++si)   // dead for S==1
#pragma unroll
            for (int ii = 0; ii < 8; ++ii) {
                f32x4 e = __builtin_nontemporal_load(
                    (const f32x4*)(eps + (size_t)si * TOT + base + (size_t)ii * PAIRS));
                ES[ii] += e;
            }

#pragma unroll
        for (int ii = 0; ii < 8; ++ii) {
            float e1x = __expf(0.5f * LV[ii].x);
            float e1y = __expf(0.5f * LV[ii].y);
            float e1z = __expf(0.5f * LV[ii].z);
            float e1w = __expf(0.5f * LV[ii].w);
            s.x += Sf * M[ii].x + ES[ii].x * e1x;
            s.y += Sf * M[ii].y + ES[ii].y * e1y;
            s.z += Sf * M[ii].z + ES[ii].z * e1z;
            s.w += Sf * M[ii].w + ES[ii].w * e1w;
            klp += (e1x*e1x + M[ii].x*M[ii].x - 1.f - LV[ii].x);
            klp += (e1y*e1y + M[ii].y*M[ii].y - 1.f - LV[ii].y);
            klp += (e1z*e1z + M[ii].z*M[ii].z - 1.f - LV[ii].z);
            klp += (e1w*e1w + M[ii].w*M[ii].w - 1.f - LV[ii].w);
        }
    }

    *(f32x4*)(part + (size_t)rc * PAIRS + p4) = s;

    for (int off = 32; off; off >>= 1)
        klp += __shfl_down(klp, off, 64);
    __shared__ float wsum[8];
    if ((threadIdx.x & 63) == 0) wsum[threadIdx.x >> 6] = klp;
    __syncthreads();
    if (threadIdx.x == 0) {
        float t = 0.f;
#pragma unroll
        for (int i = 0; i < 8; ++i) t += wsum[i];
        klpart[blockIdx.x] = t;
    }
}

// ---------------------------------------------------------------------------
// K_mid v2 (slim): 129 blocks x 512 thr.
//   0..63   csum reduce -> wct[*,512..575]
//   64..127 W^T -> wct cols 0..511
//   128     kl final + rbf-counter reset
// rbf moved to k3 (overlaps GEMM); xbf eliminated (k3 converts in-register).
// ---------------------------------------------------------------------------
__global__ __launch_bounds__(512)
void k_mid2(const float* __restrict__ part,
            const float* __restrict__ klpart,
            const float* __restrict__ bw,
            unsigned short* __restrict__ wct,
            float* __restrict__ kl_out,
            int* __restrict__ counter,
            float inv_S) {
    __shared__ float shbuf[64 * 68];   // 17.4 KB (W^T tile / kl scratch)
    int bid = blockIdx.x, t = threadIdx.x;

    if (bid < 64) {
        // ---- csum reduce: 64 blocks x 512 pairs ----
        int p = bid * 512 + t;
        float a0 = 0.f, a1 = 0.f, a2 = 0.f, a3 = 0.f;
#pragma unroll
        for (int r = 0; r < RCH; r += 4) {
            a0 += part[(size_t)(r + 0) * PAIRS + p];
            a1 += part[(size_t)(r + 1) * PAIRS + p];
            a2 += part[(size_t)(r + 2) * PAIRS + p];
            a3 += part[(size_t)(r + 3) * PAIRS + p];
        }
        int o = p >> 6, n = p & 63;
        wct[(size_t)o * KTOT + IN_F + n] = f2bf(((a0 + a1) + (a2 + a3)) * inv_S);
    } else if (bid < 128) {
        // ---- W transpose -> wct cols 0..511 ----
        float* tile = shbuf;               // 64 x 68
        int bb = bid - 64;
        int bi = bb >> 3, bj = bb & 7;
        int cq = t & 15, rq = t >> 4;      // rq 0..31
#pragma unroll
        for (int rr = 0; rr < 2; ++rr) {
            int row = rq * 2 + rr;
            float4 v = *(const float4*)(bw + (size_t)(bi * 64 + row) * OUT_F + bj * 64 + cq * 4);
            *(float4*)&tile[row * 68 + cq * 4] = v;
        }
        __syncthreads();
#pragma unroll
        for (int rr = 0; rr < 2; ++rr) {
            int orow = rq * 2 + rr;
            ushort4 w;
            w.x = f2bf(tile[(cq * 4 + 0) * 68 + orow]);
            w.y = f2bf(tile[(cq * 4 + 1) * 68 + orow]);
            w.z = f2bf(tile[(cq * 4 + 2) * 68 + orow]);
            w.w = f2bf(tile[(cq * 4 + 3) * 68 + orow]);
            *(ushort4*)(wct + (size_t)(bj * 64 + orow) * KTOT + bi * 64 + cq * 4) = w;
        }
    } else {
        // ---- kl final (512 partials) + counter reset for k3's rbf gate ----
        if (t == 0) *counter = 0;          // stream-ordered before k3
        float v = klpart[t];
        for (int off = 32; off; off >>= 1)
            v += __shfl_down(v, off, 64);
        float* wsum = shbuf;
        if ((t & 63) == 0) wsum[t >> 6] = v;
        __syncthreads();
        if (t == 0) {
            float s = 0.f;
#pragma unroll
            for (int i = 0; i < 8; ++i) s += wsum[i];
            kl_out[0] = 0.5f * s;
        }
    }
}

// ---------------------------------------------------------------------------
// K3 v5: 768 blocks x 256 thr.
//   bids 0..255  : rbf prep (x,centers -> rbf bf16), release counter.
//   bids 256..767: GEMM out = [x(bf16-converted) | rbf] @ Wc^T.
// GEMM spins on the counter only before its LAST K-iter (it==8), so the
// rbf compute hides under GEMM iters 0..7. rbf blocks are FIRST in dispatch
// order and dependency-free -> always scheduled -> no deadlock at any
// occupancy. A-operand converted f32->bf16 in-register (xbf buffer gone;
// bitwise-identical numerics to the old staging path).
// ---------------------------------------------------------------------------
__global__ __launch_bounds__(256)
void k3_fused(const float* __restrict__ x,
              const float* __restrict__ centers,
              const float* __restrict__ log_sigma,
              const unsigned short* __restrict__ wct,
              unsigned short* __restrict__ rbf,
              float* __restrict__ out,
              int* __restrict__ counter) {
    __shared__ __align__(16) unsigned short As[64 * 72];   // 9 KB
    __shared__ __align__(16) unsigned short Bs[64 * 72];   // 9 KB
    __shared__ float red[16][4][64];                       // 16 KB (rbf)
    int t = threadIdx.x;
    int bid = blockIdx.x;

    if (bid < 256) {
        // =================== rbf prep: rows bid*16..+16 ===================
        int n = t & 63;                  // center
        int wu = t >> 6;                 // 0..3: dim-quarter (128 dims, 2 halves)
        int b0 = bid * 16;

        float dacc[16];
#pragma unroll
        for (int bi = 0; bi < 16; ++bi) dacc[bi] = 0.f;

        for (int h = 0; h < 2; ++h) {
            float creg[64];
#pragma unroll
            for (int q = 0; q < 16; ++q) {
                float4 v = *(const float4*)(centers + (size_t)n * IN_F + wu * 128 + h * 64 + q * 4);
                creg[q * 4 + 0] = v.x; creg[q * 4 + 1] = v.y;
                creg[q * 4 + 2] = v.z; creg[q * 4 + 3] = v.w;
            }
#pragma unroll
            for (int bi = 0; bi < 16; ++bi) {
                const float* xr = x + (size_t)(b0 + bi) * IN_F + wu * 128 + h * 64;
                float d0 = 0.f, d1 = 0.f, d2 = 0.f, d3 = 0.f;
#pragma unroll
                for (int j = 0; j < 64; j += 4) {
                    float t0 = xr[j + 0] - creg[j + 0];
                    float t1 = xr[j + 1] - creg[j + 1];
                    float t2 = xr[j + 2] - creg[j + 2];
                    float t3 = xr[j + 3] - creg[j + 3];
                    d0 = fmaf(t0, t0, d0); d1 = fmaf(t1, t1, d1);
                    d2 = fmaf(t2, t2, d2); d3 = fmaf(t3, t3, d3);
                }
                dacc[bi] += (d0 + d1) + (d2 + d3);
            }
        }
#pragma unroll
        for (int bi = 0; bi < 16; ++bi)
            red[bi][wu][n] = dacc[bi];
        __syncthreads();
#pragma unroll
        for (int pass = 0; pass < 4; ++pass) {
            int idx = pass * 256 + t;    // 1024 outputs: 16 rows x 64 centers
            int bi = idx >> 6, nn = idx & 63;
            float ssum = red[bi][0][nn] + red[bi][1][nn] + red[bi][2][nn] + red[bi][3][nn];
            float sg  = __expf(log_sigma[nn]);
            float inv = 1.f / (2.f * sg * sg + 1e-8f);
            rbf[(size_t)(b0 + bi) * NC + nn] = f2bf(__expf(-ssum * inv));
        }
        __threadfence();     // make rbf stores visible device-wide
        __syncthreads();
        if (t == 0)
            __hip_atomic_fetch_add(counter, 1, __ATOMIC_RELEASE, __HIP_MEMORY_SCOPE_AGENT);
        return;
    }

    // =================== GEMM: bids 256..767 ===================
    int gb = bid - 256;
    int bm = gb >> 3, bn = gb & 7;
    int b0 = bm * 64, o0 = bn * 64;
    int ar = t & 63, ah = t >> 6;        // staging: row, k-quarter(16)
    int lane = t & 63, wv = t >> 6;
    int fm = lane & 15, kg = lane >> 4;

    f32x4 acc[4] = {{0,0,0,0},{0,0,0,0},{0,0,0,0},{0,0,0,0}};
    const int abase = (wv * 16 + fm) * 72 + kg * 8;
    const int soff  = ar * 72 + ah * 16;

    for (int it = 0; it < 9; ++it) {
        if (it == 8) {
            // wait for all 256 rbf blocks before reading rbf
            if (t == 0) {
                while (__hip_atomic_load(counter, __ATOMIC_ACQUIRE,
                                         __HIP_MEMORY_SCOPE_AGENT) < 256) {}
            }
            __syncthreads();
        }
        bf16x8 av0, av1, bv0, bv1;
        if (it < 8) {
            int k0 = it * 64;
            // A: x f32 -> bf16 in-register (identical RNE to old xbf path)
            const float* xp = x + (size_t)(b0 + ar) * IN_F + k0 + ah * 16;
            f32x4 a0 = *(const f32x4*)(xp);
            f32x4 a1 = *(const f32x4*)(xp + 4);
            f32x4 a2 = *(const f32x4*)(xp + 8);
            f32x4 a3 = *(const f32x4*)(xp + 12);
            av0[0] = (short)f2bf(a0.x); av0[1] = (short)f2bf(a0.y);
            av0[2] = (short)f2bf(a0.z); av0[3] = (short)f2bf(a0.w);
            av0[4] = (short)f2bf(a1.x); av0[5] = (short)f2bf(a1.y);
            av0[6] = (short)f2bf(a1.z); av0[7] = (short)f2bf(a1.w);
            av1[0] = (short)f2bf(a2.x); av1[1] = (short)f2bf(a2.y);
            av1[2] = (short)f2bf(a2.z); av1[3] = (short)f2bf(a2.w);
            av1[4] = (short)f2bf(a3.x); av1[5] = (short)f2bf(a3.y);
            av1[6] = (short)f2bf(a3.z); av1[7] = (short)f2bf(a3.w);
            bv0 = *(const bf16x8*)(wct + (size_t)(o0 + ar) * KTOT + k0 + ah * 16);
            bv1 = *(const bf16x8*)(wct + (size_t)(o0 + ar) * KTOT + k0 + ah * 16 + 8);
        } else {
            av0 = *(const bf16x8*)(rbf + (size_t)(b0 + ar) * NC + ah * 16);
            av1 = *(const bf16x8*)(rbf + (size_t)(b0 + ar) * NC + ah * 16 + 8);
            bv0 = *(const bf16x8*)(wct + (size_t)(o0 + ar) * KTOT + IN_F + ah * 16);
            bv1 = *(const bf16x8*)(wct + (size_t)(o0 + ar) * KTOT + IN_F + ah * 16 + 8);
        }
        __syncthreads();
        *(bf16x8*)&As[soff]     = av0;
        *(bf16x8*)&As[soff + 8] = av1;
        *(bf16x8*)&Bs[soff]     = bv0;
        *(bf16x8*)&Bs[soff + 8] = bv1;
        __syncthreads();
        bf16x8 af0 = *(bf16x8*)&As[abase];
        bf16x8 af1 = *(bf16x8*)&As[abase + 32];
#pragma unroll
        for (int nf = 0; nf < 4; ++nf) {
            bf16x8 b0f = *(bf16x8*)&Bs[(nf * 16 + fm) * 72 + kg * 8];
            acc[nf] = __builtin_amdgcn_mfma_f32_16x16x32_bf16(af0, b0f, acc[nf], 0, 0, 0);
            bf16x8 b1f = *(bf16x8*)&Bs[(nf * 16 + fm) * 72 + 32 + kg * 8];
            acc[nf] = __builtin_amdgcn_mfma_f32_16x16x32_bf16(af1, b1f, acc[nf], 0, 0, 0);
        }
    }

    // epilogue: C/D layout col=lane&15, row=(lane>>4)*4+reg
#pragma unroll
    for (int nf = 0; nf < 4; ++nf)
#pragma unroll
        for (int rr = 0; rr < 4; ++rr)
            out[(size_t)(b0 + wv * 16 + kg * 4 + rr) * OUT_F + o0 + nf * 16 + fm] = acc[nf][rr];
}

// ---------------------------------------------------------------------------
extern "C" void kernel_launch(void* const* d_in, const int* in_sizes, int n_in,
                              void* d_out, int out_size, void* d_ws, size_t ws_size,
                              hipStream_t stream) {
    const float* x         = (const float*)d_in[0];
    const float* centers   = (const float*)d_in[1];
    const float* log_sigma = (const float*)d_in[2];
    const float* cm        = (const float*)d_in[3];
    const float* clv       = (const float*)d_in[4];
    const float* bw        = (const float*)d_in[5];
    const float* eps       = (const float*)d_in[6];

    float* out = (float*)d_out;
    float* kl  = out + (size_t)B_SZ * OUT_F;

    // ws: [part 4MB][klpart 2KB][WcT 576KB bf16][rbf 512KB bf16][counter 4B]
    float* part   = (float*)d_ws;
    float* klpart = part + (size_t)RCH * PAIRS;
    unsigned short* wct = (unsigned short*)(klpart + 512);
    unsigned short* rbf = wct + (size_t)OUT_F * KTOT;
    int* counter = (int*)(rbf + (size_t)B_SZ * NC);

    int S = in_sizes[6] / TOT;   // = 1

    k1_partial<<<512, 512, 0, stream>>>(cm, clv, eps, part, klpart, S);
    k_mid2<<<129, 512, 0, stream>>>(part, klpart, bw, wct, kl, counter,
                                    1.0f / (float)S);
    k3_fused<<<768, 256, 0, stream>>>(x, centers, log_sigma, wct, rbf,
                                      out, counter);
}

// Round 8
// 225.793 us; speedup vs baseline: 1.2454x; 1.2454x over previous
//
#include <hip/hip_runtime.h>
#include <hip/hip_bf16.h>

#define B_SZ  4096
#define IN_F  512
#define OUT_F 512
#define NC    64
#define PAIRS 32768               // OUT_F * NC
#define TOT   (IN_F * PAIRS)      // 16.8M
#define KTOT  (IN_F + NC)         // 576: combined GEMM K
#define RCH   32                  // k1 row-chunks (16 rows each)

typedef __attribute__((ext_vector_type(8))) short bf16x8;
typedef __attribute__((ext_vector_type(4))) float f32x4;

static __device__ inline unsigned short f2bf(float f) {
    __hip_bfloat16 h = __float2bfloat16(f);   // RNE
    return *(unsigned short*)&h;
}

// ---------------------------------------------------------------------------
// K1: partial c_sum + kl — EXACT R1 standalone configuration (46.6 us,
// 2.25 TB/s HBM). R3/R4 proved ANY co-scheduled prep loses. Do not touch.
// ---------------------------------------------------------------------------
__global__ __launch_bounds__(512)
void k1_partial(const float* __restrict__ cm,
                const float* __restrict__ clv,
                const float* __restrict__ eps,
                float* __restrict__ part,
                float* __restrict__ klpart,
                int S) {
    int pb = blockIdx.x & 15;            // pair-slice: 2048 pairs (8 KB/row)
    int rc = blockIdx.x >> 4;            // row-chunk: rows rc*16..+16
    int p4 = pb * 2048 + (threadIdx.x << 2);
    float Sf = (float)S;

    f32x4 s = {0.f, 0.f, 0.f, 0.f};
    float klp = 0.f;

    for (int g = 0; g < 2; ++g) {
        size_t base = (size_t)(rc * 16 + g * 8) * PAIRS + p4;
        f32x4 M[8], LV[8], ES[8];
#pragma unroll
        for (int ii = 0; ii < 8; ++ii)
            M[ii] = __builtin_nontemporal_load((const f32x4*)(cm + base + (size_t)ii * PAIRS));
#pragma unroll
        for (int ii = 0; ii < 8; ++ii)
            LV[ii] = __builtin_nontemporal_load((const f32x4*)(clv + base + (size_t)ii * PAIRS));
#pragma unroll
        for (int ii = 0; ii < 8; ++ii)
            ES[ii] = __builtin_nontemporal_load((const f32x4*)(eps + base + (size_t)ii * PAIRS));
        for (int si = 1; si < S; ++si)   // dead for S==1
#pragma unroll
            for (int ii = 0; ii < 8; ++ii) {
                f32x4 e = __builtin_nontemporal_load(
                    (const f32x4*)(eps + (size_t)si * TOT + base + (size_t)ii * PAIRS));
                ES[ii] += e;
            }

#pragma unroll
        for (int ii = 0; ii < 8; ++ii) {
            float e1x = __expf(0.5f * LV[ii].x);
            float e1y = __expf(0.5f * LV[ii].y);
            float e1z = __expf(0.5f * LV[ii].z);
            float e1w = __expf(0.5f * LV[ii].w);
            s.x += Sf * M[ii].x + ES[ii].x * e1x;
            s.y += Sf * M[ii].y + ES[ii].y * e1y;
            s.z += Sf * M[ii].z + ES[ii].z * e1z;
            s.w += Sf * M[ii].w + ES[ii].w * e1w;
            klp += (e1x*e1x + M[ii].x*M[ii].x - 1.f - LV[ii].x);
            klp += (e1y*e1y + M[ii].y*M[ii].y - 1.f - LV[ii].y);
            klp += (e1z*e1z + M[ii].z*M[ii].z - 1.f - LV[ii].z);
            klp += (e1w*e1w + M[ii].w*M[ii].w - 1.f - LV[ii].w);
        }
    }

    *(f32x4*)(part + (size_t)rc * PAIRS + p4) = s;

    for (int off = 32; off; off >>= 1)
        klp += __shfl_down(klp, off, 64);
    __shared__ float wsum[8];
    if ((threadIdx.x & 63) == 0) wsum[threadIdx.x >> 6] = klp;
    __syncthreads();
    if (threadIdx.x == 0) {
        float t = 0.f;
#pragma unroll
        for (int i = 0; i < 8; ++i) t += wsum[i];
        klpart[blockIdx.x] = t;
    }
}

// ---------------------------------------------------------------------------
// K_mid v3: 193 blocks x 512 thr.
//   0..63   rbf via MFMA (dist^2 = ||x||^2 + ||c||^2 - 2 x.c) + xbf emit
//   64..127 csum reduce -> wct[*,512..575]
//   128..191 W^T -> wct cols 0..511
//   192     kl final
// R6 lesson: rbf as VALU (sub+fma chains, wave-uniform scalar loads) was
// ~12us; x.c is a 4096x64x512 GEMM -> MFMA (~2us). bf16 rounding enters only
// the xc cross-term: +-0.2 abs on dist^2 ~ 1000 -> rbf=exp(-~500)=0 either way.
// ---------------------------------------------------------------------------
__global__ __launch_bounds__(512)
void k_mid3(const float* __restrict__ x,
            const float* __restrict__ centers,
            const float* __restrict__ log_sigma,
            const float* __restrict__ part,
            const float* __restrict__ klpart,
            const float* __restrict__ bw,
            unsigned short* __restrict__ rbf,
            unsigned short* __restrict__ wct,
            unsigned short* __restrict__ xbf,
            float* __restrict__ kl_out,
            float inv_S) {
    __shared__ __align__(16) float shbuf[5312];   // 21.25 KB, aliased per role
    int bid = blockIdx.x, t = threadIdx.x;

    if (bid < 64) {
        // =================== rbf-MFMA: rows b0..b0+63, all 64 centers ========
        unsigned short* As = (unsigned short*)shbuf;           // [64][72] bf16
        unsigned short* Cs = (unsigned short*)(shbuf + 2304);  // [64][72] bf16
        float* scr = shbuf + 4608;   // [512] partial scratch (cn, then xn)
        float* cn  = shbuf + 5120;   // [64] ||c||^2
        float* inv = shbuf + 5184;   // [64] 1/(2 sg^2 + 1e-8)
        float* xnf = shbuf + 5248;   // [64] ||x||^2

        int b0 = bid * 64;

        // ---- center norms + inv (f32 exact) ----
        {
            int n = t & 63, p = t >> 6;
            const float* cp = centers + (size_t)n * IN_F + p * 64;
            float s0 = 0.f, s1 = 0.f, s2 = 0.f, s3 = 0.f;
#pragma unroll
            for (int j = 0; j < 64; j += 4) {
                float4 v = *(const float4*)(cp + j);
                s0 = fmaf(v.x, v.x, s0); s1 = fmaf(v.y, v.y, s1);
                s2 = fmaf(v.z, v.z, s2); s3 = fmaf(v.w, v.w, s3);
            }
            scr[p * 64 + n] = (s0 + s1) + (s2 + s3);
        }
        __syncthreads();
        if (t < 64) {
            float s = 0.f;
#pragma unroll
            for (int p = 0; p < 8; ++p) s += scr[p * 64 + t];
            cn[t] = s;
            float sg = __expf(log_sigma[t]);
            inv[t] = 1.f / (2.f * sg * sg + 1e-8f);
        }
        __syncthreads();

        // ---- main loop: stage x/c tiles (f32->bf16), MFMA xc, emit xbf ----
        int ar = t >> 3, ah = t & 7;             // staging: row, k-octant(8)
        int lane = t & 63, wv = t >> 6;          // wv 0..7; MFMA on wv<4
        int fm = lane & 15, kg = lane >> 4;
        float xacc = 0.f;
        f32x4 acc[4] = {{0,0,0,0},{0,0,0,0},{0,0,0,0},{0,0,0,0}};

        for (int it = 0; it < 8; ++it) {
            int k0 = it * 64;
            const float* xp = x + (size_t)(b0 + ar) * IN_F + k0 + ah * 8;
            f32x4 v0 = *(const f32x4*)(xp);
            f32x4 v1 = *(const f32x4*)(xp + 4);
            const float* cp = centers + (size_t)ar * IN_F + k0 + ah * 8;
            f32x4 c0 = *(const f32x4*)(cp);
            f32x4 c1 = *(const f32x4*)(cp + 4);
            bf16x8 xb, cb;
            xb[0] = (short)f2bf(v0.x); xb[1] = (short)f2bf(v0.y);
            xb[2] = (short)f2bf(v0.z); xb[3] = (short)f2bf(v0.w);
            xb[4] = (short)f2bf(v1.x); xb[5] = (short)f2bf(v1.y);
            xb[6] = (short)f2bf(v1.z); xb[7] = (short)f2bf(v1.w);
            cb[0] = (short)f2bf(c0.x); cb[1] = (short)f2bf(c0.y);
            cb[2] = (short)f2bf(c0.z); cb[3] = (short)f2bf(c0.w);
            cb[4] = (short)f2bf(c1.x); cb[5] = (short)f2bf(c1.y);
            cb[6] = (short)f2bf(c1.z); cb[7] = (short)f2bf(c1.w);
            xacc += v0.x*v0.x + v0.y*v0.y + v0.z*v0.z + v0.w*v0.w
                  + v1.x*v1.x + v1.y*v1.y + v1.z*v1.z + v1.w*v1.w;
            __syncthreads();                       // prev MFMA done reading LDS
            *(bf16x8*)&As[ar * 72 + ah * 8] = xb;
            *(bf16x8*)&Cs[ar * 72 + ah * 8] = cb;
            *(bf16x8*)(xbf + (size_t)(b0 + ar) * IN_F + k0 + ah * 8) = xb;
            __syncthreads();
            if (wv < 4) {
                bf16x8 af0 = *(bf16x8*)&As[(wv * 16 + fm) * 72 + kg * 8];
                bf16x8 af1 = *(bf16x8*)&As[(wv * 16 + fm) * 72 + 32 + kg * 8];
#pragma unroll
                for (int nf = 0; nf < 4; ++nf) {
                    bf16x8 b0f = *(bf16x8*)&Cs[(nf * 16 + fm) * 72 + kg * 8];
                    acc[nf] = __builtin_amdgcn_mfma_f32_16x16x32_bf16(af0, b0f, acc[nf], 0, 0, 0);
                    bf16x8 b1f = *(bf16x8*)&Cs[(nf * 16 + fm) * 72 + 32 + kg * 8];
                    acc[nf] = __builtin_amdgcn_mfma_f32_16x16x32_bf16(af1, b1f, acc[nf], 0, 0, 0);
                }
            }
        }

        // ---- x row norms: reduce per-thread partials ----
        scr[ar * 8 + ah] = xacc;                   // scr last read pre-loop; safe
        __syncthreads();
        if (t < 64) {
            float s = 0.f;
#pragma unroll
            for (int p = 0; p < 8; ++p) s += scr[t * 8 + p];
            xnf[t] = s;
        }
        __syncthreads();

        // ---- epilogue: rbf = exp(-(xn + cn - 2 xc) * inv), C/D layout ----
        if (wv < 4) {
#pragma unroll
            for (int nf = 0; nf < 4; ++nf) {
                int c = nf * 16 + fm;
                float cnc = cn[c], ivc = inv[c];
#pragma unroll
                for (int rr = 0; rr < 4; ++rr) {
                    int r = wv * 16 + kg * 4 + rr;
                    float d = xnf[r] + cnc - 2.f * acc[nf][rr];
                    rbf[(size_t)(b0 + r) * NC + c] = f2bf(__expf(-d * ivc));
                }
            }
        }
    } else if (bid < 128) {
        // =================== csum reduce: 64 blocks x 512 pairs =============
        int p = (bid - 64) * 512 + t;
        float a0 = 0.f, a1 = 0.f, a2 = 0.f, a3 = 0.f;
#pragma unroll
        for (int r = 0; r < RCH; r += 4) {
            a0 += part[(size_t)(r + 0) * PAIRS + p];
            a1 += part[(size_t)(r + 1) * PAIRS + p];
            a2 += part[(size_t)(r + 2) * PAIRS + p];
            a3 += part[(size_t)(r + 3) * PAIRS + p];
        }
        int o = p >> 6, n = p & 63;
        wct[(size_t)o * KTOT + IN_F + n] = f2bf(((a0 + a1) + (a2 + a3)) * inv_S);
    } else if (bid < 192) {
        // =================== W^T -> wct cols 0..511 =========================
        float* tile = shbuf;               // 64 x 68
        int bb = bid - 128;
        int bi = bb >> 3, bj = bb & 7;
        int cq = t & 15, rq = t >> 4;      // rq 0..31
#pragma unroll
        for (int rr = 0; rr < 2; ++rr) {
            int row = rq * 2 + rr;
            float4 v = *(const float4*)(bw + (size_t)(bi * 64 + row) * OUT_F + bj * 64 + cq * 4);
            *(float4*)&tile[row * 68 + cq * 4] = v;
        }
        __syncthreads();
#pragma unroll
        for (int rr = 0; rr < 2; ++rr) {
            int orow = rq * 2 + rr;
            ushort4 w;
            w.x = f2bf(tile[(cq * 4 + 0) * 68 + orow]);
            w.y = f2bf(tile[(cq * 4 + 1) * 68 + orow]);
            w.z = f2bf(tile[(cq * 4 + 2) * 68 + orow]);
            w.w = f2bf(tile[(cq * 4 + 3) * 68 + orow]);
            *(ushort4*)(wct + (size_t)(bj * 64 + orow) * KTOT + bi * 64 + cq * 4) = w;
        }
    } else {
        // =================== kl final: 512 partials =========================
        float v = klpart[t];
        for (int off = 32; off; off >>= 1)
            v += __shfl_down(v, off, 64);
        float* wsum = shbuf;
        if ((t & 63) == 0) wsum[t >> 6] = v;
        __syncthreads();
        if (t == 0) {
            float s = 0.f;
#pragma unroll
            for (int i = 0; i < 8; ++i) s += wsum[i];
            kl_out[0] = 0.5f * s;
        }
    }
}

// ---------------------------------------------------------------------------
// K3: EXACT R1 version (proven, ~25us): out = [xbf | rbf] @ Wc^T via
// mfma_f32_16x16x32_bf16. BM=BN=64, BK=64, grid 512, 256 thr, 9 K-iters.
// ---------------------------------------------------------------------------
__global__ __launch_bounds__(256)
void k3_mfma(const unsigned short* __restrict__ xbf,
             const unsigned short* __restrict__ rbf,
             const unsigned short* __restrict__ wct,
             float* __restrict__ out) {
    __shared__ __align__(16) unsigned short As[64 * 72];   // 9 KB
    __shared__ __align__(16) unsigned short Bs[64 * 72];   // 9 KB
    int t = threadIdx.x;
    int bm = blockIdx.x >> 3, bn = blockIdx.x & 7;
    int b0 = bm * 64, o0 = bn * 64;
    int ar = t & 63, ah = t >> 6;        // staging: row, k-quarter(16)
    int lane = t & 63, wv = t >> 6;
    int fm = lane & 15, kg = lane >> 4;

    f32x4 acc[4] = {{0,0,0,0},{0,0,0,0},{0,0,0,0},{0,0,0,0}};
    const int abase = (wv * 16 + fm) * 72 + kg * 8;
    const int soff  = ar * 72 + ah * 16;

    for (int it = 0; it < 9; ++it) {
        bf16x8 av0, av1, bv0, bv1;
        if (it < 8) {
            int k0 = it * 64;
            av0 = *(const bf16x8*)(xbf + (size_t)(b0 + ar) * IN_F + k0 + ah * 16);
            av1 = *(const bf16x8*)(xbf + (size_t)(b0 + ar) * IN_F + k0 + ah * 16 + 8);
            bv0 = *(const bf16x8*)(wct + (size_t)(o0 + ar) * KTOT + k0 + ah * 16);
            bv1 = *(const bf16x8*)(wct + (size_t)(o0 + ar) * KTOT + k0 + ah * 16 + 8);
        } else {
            av0 = *(const bf16x8*)(rbf + (size_t)(b0 + ar) * NC + ah * 16);
            av1 = *(const bf16x8*)(rbf + (size_t)(b0 + ar) * NC + ah * 16 + 8);
            bv0 = *(const bf16x8*)(wct + (size_t)(o0 + ar) * KTOT + IN_F + ah * 16);
            bv1 = *(const bf16x8*)(wct + (size_t)(o0 + ar) * KTOT + IN_F + ah * 16 + 8);
        }
        __syncthreads();
        *(bf16x8*)&As[soff]     = av0;
        *(bf16x8*)&As[soff + 8] = av1;
        *(bf16x8*)&Bs[soff]     = bv0;
        *(bf16x8*)&Bs[soff + 8] = bv1;
        __syncthreads();
        bf16x8 af0 = *(bf16x8*)&As[abase];
        bf16x8 af1 = *(bf16x8*)&As[abase + 32];
#pragma unroll
        for (int nf = 0; nf < 4; ++nf) {
            bf16x8 b0f = *(bf16x8*)&Bs[(nf * 16 + fm) * 72 + kg * 8];
            acc[nf] = __builtin_amdgcn_mfma_f32_16x16x32_bf16(af0, b0f, acc[nf], 0, 0, 0);
            bf16x8 b1f = *(bf16x8*)&Bs[(nf * 16 + fm) * 72 + 32 + kg * 8];
            acc[nf] = __builtin_amdgcn_mfma_f32_16x16x32_bf16(af1, b1f, acc[nf], 0, 0, 0);
        }
    }

    // epilogue: C/D layout col=lane&15, row=(lane>>4)*4+reg
#pragma unroll
    for (int nf = 0; nf < 4; ++nf)
#pragma unroll
        for (int rr = 0; rr < 4; ++rr)
            out[(size_t)(b0 + wv * 16 + kg * 4 + rr) * OUT_F + o0 + nf * 16 + fm] = acc[nf][rr];
}

// ---------------------------------------------------------------------------
extern "C" void kernel_launch(void* const* d_in, const int* in_sizes, int n_in,
                              void* d_out, int out_size, void* d_ws, size_t ws_size,
                              hipStream_t stream) {
    const float* x         = (const float*)d_in[0];
    const float* centers   = (const float*)d_in[1];
    const float* log_sigma = (const float*)d_in[2];
    const float* cm        = (const float*)d_in[3];
    const float* clv       = (const float*)d_in[4];
    const float* bw        = (const float*)d_in[5];
    const float* eps       = (const float*)d_in[6];

    float* out = (float*)d_out;
    float* kl  = out + (size_t)B_SZ * OUT_F;

    // ws: [part 4MB][klpart 2KB][WcT 576KB bf16][rbf 512KB bf16][xbf 4MB bf16]
    float* part   = (float*)d_ws;
    float* klpart = part + (size_t)RCH * PAIRS;
    unsigned short* wct = (unsigned short*)(klpart + 512);
    unsigned short* rbf = wct + (size_t)OUT_F * KTOT;
    unsigned short* xbf = rbf + (size_t)B_SZ * NC;

    int S = in_sizes[6] / TOT;   // = 1

    k1_partial<<<512, 512, 0, stream>>>(cm, clv, eps, part, klpart, S);
    k_mid3<<<193, 512, 0, stream>>>(x, centers, log_sigma, part, klpart, bw,
                                    rbf, wct, xbf, kl, 1.0f / (float)S);
    k3_mfma<<<(B_SZ / 64) * (OUT_F / 64), 256, 0, stream>>>(xbf, rbf, wct, out);
}